// Round 9
// baseline (259.374 us; speedup 1.0000x reference)
//
#include <hip/hip_runtime.h>

#define NH 16
#define SLEN 2048
#define DMODEL 1024
#define DHEAD 64
#define WIN 512
#define NB 4

typedef unsigned short u16;
typedef unsigned int u32;
typedef unsigned long long u64;
typedef __attribute__((ext_vector_type(8))) __bf16 bf16x8;
typedef __attribute__((ext_vector_type(4))) float floatx4;

__device__ __forceinline__ float b2f(u32 bits16) {
  union { u32 i; float f; } x; x.i = bits16 << 16; return x.f;
}
__device__ __forceinline__ u16 f2b(float f) {
  union { float f; u32 i; } x; x.f = f;
  u32 r = x.i + 0x7fffu + ((x.i >> 16) & 1u);
  return (u16)(r >> 16);
}

// async global->LDS, 16B/lane; LDS dest must be wave-uniform base + lane*16
__device__ __forceinline__ void gl2lds16(const u16* g, u16* l) {
  __builtin_amdgcn_global_load_lds(
      (const __attribute__((address_space(1))) unsigned int*)g,
      (__attribute__((address_space(3))) unsigned int*)l, 16, 0, 0);
}

// inline-asm LDS read: invisible to compiler alias analysis; completion is
// managed by explicit counted lgkmcnt + sched_barrier(0) (rule #18).
template<int OFF>
__device__ __forceinline__ bf16x8 ldsr128(u32 addr) {
  bf16x8 r;
  if constexpr (OFF == 0)
    asm volatile("ds_read_b128 %0, %1" : "=v"(r) : "v"(addr));
  else
    asm volatile("ds_read_b128 %0, %1 offset:%2" : "=v"(r) : "v"(addr), "i"(OFF));
  return r;
}

#define WAIT_VM8   asm volatile("s_waitcnt vmcnt(8)" ::: "memory")
#define WAIT_VM0   asm volatile("s_waitcnt vmcnt(0)" ::: "memory")
#define WAIT_LGKM8 asm volatile("s_waitcnt lgkmcnt(8)" ::: "memory")
#define WAIT_LGKM0 asm volatile("s_waitcnt lgkmcnt(0)" ::: "memory")
#define SCHEDB     __builtin_amdgcn_sched_barrier(0)

// ---------------- fused prep: cvt + weight packs + rotary table ----------------
__global__ __launch_bounds__(256) void prep_all(
    const float* __restrict__ tokens, const float* __restrict__ Wq,
    const float* __restrict__ Wkv, const float* __restrict__ Wout,
    const float* __restrict__ Wmix, const float* __restrict__ Wgate,
    u64* __restrict__ tokA64, u16* __restrict__ WqkvT, u16* __restrict__ WoutT,
    u16* __restrict__ Wmg, float2* __restrict__ rtab) {
  __shared__ u16 T[64][72];
  const int blk = blockIdx.x, tid = threadIdx.x;
  if (blk < 8192) {
    int i = blk * 256 + tid;
    float4 f = reinterpret_cast<const float4*>(tokens)[i];
    union { u16 u[4]; u64 ll; } pk;
    pk.u[0] = f2b(f.x); pk.u[1] = f2b(f.y); pk.u[2] = f2b(f.z); pk.u[3] = f2b(f.w);
    tokA64[i] = pk.ll;
  } else if (blk < 9216) {
    const float* src; u16* dst; int ld, nb, n0, k0;
    if (blk < 8960) {
      int tile = blk - 8192;                      // 48 n-tiles x 16 k-tiles
      n0 = (tile % 48) * 64; k0 = (tile / 48) * 64;
      if (n0 < 1024) { src = Wq; ld = 1024; nb = n0; }
      else { src = Wkv; ld = 2048; nb = n0 - 1024; }
      dst = WqkvT;
    } else {
      int tile = blk - 8960;                      // 16 x 16
      n0 = (tile % 16) * 64; k0 = (tile / 16) * 64;
      src = Wout; ld = 1024; nb = n0; dst = WoutT;
    }
#pragma unroll
    for (int i = 0; i < 16; ++i) {
      int e = i * 256 + tid;
      int kr = e >> 6, nc = e & 63;
      T[kr][nc] = f2b(src[(size_t)(k0 + kr) * ld + nb + nc]);
    }
    __syncthreads();
#pragma unroll
    for (int i = 0; i < 16; ++i) {
      int e = i * 256 + tid;
      int nr = e >> 6, kc = e & 63;
      dst[(size_t)(n0 + nr) * 1024 + k0 + kc] = T[kc][nr];
    }
  } else if (blk < 9344) {
    int idx = (blk - 9216) * 256 + tid;           // 32768
    int n = idx >> 10, k = idx & 1023;
    float v = (n < 16) ? Wmix[k * 16 + n] : Wgate[k * 16 + (n - 16)];
    Wmg[idx] = f2b(v);
  } else {
    int idx = (blk - 9344) * 256 + tid;           // 65536
    int s = idx >> 5, t = idx & 31;
    float inv = __expf((float)t * -0.2878231366f);
    float ang = (float)s * inv;
    float sn, cs;
    __sincosf(ang, &sn, &cs);
    rtab[idx] = make_float2(cs, sn);
  }
}

// ---------------- mix / gate via MFMA (2 waves/block, 16-row strips, 256 blocks) ----
__global__ __launch_bounds__(128) void mixgate_mfma(const u16* __restrict__ A,
    const u16* __restrict__ Wmg, float* __restrict__ mixws, float* __restrict__ gatews) {
  const int lane = threadIdx.x & 63, w = threadIdx.x >> 6;
  const int lm = lane & 15, quad = lane >> 4;
  const int row0 = (blockIdx.x * 2 + w) * 16;

  floatx4 acc[2];
  acc[0] = (floatx4){0.f, 0.f, 0.f, 0.f};
  acc[1] = (floatx4){0.f, 0.f, 0.f, 0.f};

#pragma unroll 4
  for (int k0 = 0; k0 < 1024; k0 += 32) {
    bf16x8 af = *reinterpret_cast<const bf16x8*>(
        &A[(size_t)(row0 + lm) * 1024 + k0 + quad * 8]);
    bf16x8 bf[2];
#pragma unroll
    for (int nt = 0; nt < 2; ++nt)
      bf[nt] = *reinterpret_cast<const bf16x8*>(
          &Wmg[(size_t)(nt * 16 + lm) * 1024 + k0 + quad * 8]);
#pragma unroll
    for (int nt = 0; nt < 2; ++nt)
      acc[nt] = __builtin_amdgcn_mfma_f32_16x16x32_bf16(af, bf[nt], acc[nt], 0, 0, 0);
  }

#pragma unroll
  for (int r = 0; r < 4; ++r) {
    int grow = row0 + quad * 4 + r;
    int b = grow >> 11, s = grow & 2047;
#pragma unroll
    for (int nt = 0; nt < 2; ++nt) {
      int n = nt * 16 + lm;
      float sig = 1.0f / (1.0f + __expf(-acc[nt][r]));
      int h = n & 15;
      (n < 16 ? mixws : gatews)[(b * NH + h) * SLEN + s] = sig;
    }
  }
}

// ---------------- m97-geometry MFMA bf16 GEMM: 128x128, 2 blocks/CU (r8 best) ----
template<int MODE>
__global__ __launch_bounds__(256, 2) void gemm_pipe(
    const u16* __restrict__ A, const u16* __restrict__ Bt,
    float* __restrict__ C,
    u16* __restrict__ qws, u16* __restrict__ kws, u16* __restrict__ vws,
    const float* __restrict__ vres, const float* __restrict__ mixws,
    const float2* __restrict__ rtab, int N) {
  __shared__ u16 smem[32768];                     // 64KB: 2 x (A 16KB + B 16KB)
  const int tid = threadIdx.x;
  const int nbx = N >> 7;
  const int wg = (blockIdx.x & 7) * (gridDim.x >> 3) + (blockIdx.x >> 3);
  const int bx = wg % nbx, by = wg / nbx;
  const int row0 = by * 128, col0 = bx * 128;
  const int w = tid >> 6, lane = tid & 63;
  const int wr = (w >> 1) * 64, wc = (w & 1) * 64;
  const int lm = lane & 15, quad = lane >> 4;
  const int NT = 16;                              // K = 1024, BK = 64
  const int sr = tid >> 3, sc = tid & 7;          // staging: rows sr+{0,32,64,96}
  const int sl0 = (sr * 8 + sc) * 8;              // u16 offset in tile region
  const u16* gA = A + (size_t)(row0 + sr) * 1024 + ((sc ^ (sr & 7)) << 3);
  const u16* gB = Bt + (size_t)(col0 + sr) * 1024 + ((sc ^ (sr & 7)) << 3);

  const u32 ldsbase = (u32)(size_t)(__attribute__((address_space(3))) u16*)smem;
  u32 arow[2], brow[2];                           // byte offsets within buffer
#pragma unroll
  for (int j = 0; j < 2; ++j) {
    u32 cslot = (u32)((j * 4 + quad) ^ (lm & 7));
    arow[j] = (u32)(wr + lm) * 128 + cslot * 16;
    brow[j] = 16384u + (u32)(wc + lm) * 128 + cslot * 16;
  }

  floatx4 acc[4][4];
#pragma unroll
  for (int i = 0; i < 4; ++i)
#pragma unroll
    for (int j = 0; j < 4; ++j)
      acc[i][j] = (floatx4){0.f, 0.f, 0.f, 0.f};

  auto stage8 = [&](int buf, int t2) {            // full tile: 8 x 4KB loads
    const int ks = t2 << 6;
    u16* Sa = smem + buf * 16384;
    u16* Sb = Sa + 8192;
    gl2lds16(gA + ks, Sa + sl0);
    gl2lds16(gA + 32 * 1024 + ks, Sa + 2048 + sl0);
    gl2lds16(gA + 64 * 1024 + ks, Sa + 4096 + sl0);
    gl2lds16(gA + 96 * 1024 + ks, Sa + 6144 + sl0);
    gl2lds16(gB + ks, Sb + sl0);
    gl2lds16(gB + 32 * 1024 + ks, Sb + 2048 + sl0);
    gl2lds16(gB + 64 * 1024 + ks, Sb + 4096 + sl0);
    gl2lds16(gB + 96 * 1024 + ks, Sb + 6144 + sl0);
  };

  stage8(0, 0);                                   // prologue
  for (int t = 0; t < NT; ++t) {
    const int cur = t & 1;
    const u32 abase = ldsbase + (u32)cur * 32768u;

    __builtin_amdgcn_s_barrier();                 // B_top: buf[cur^1] readers done
    if (t + 1 < NT) { stage8(cur ^ 1, t + 1); WAIT_VM8; }
    else            { WAIT_VM0; }
    __builtin_amdgcn_s_barrier();                 // B_mid: ALL tile-t loads landed
    SCHEDB;

    const u32 a0 = abase + arow[0], b0 = abase + brow[0];
    const u32 a1 = abase + arow[1], b1 = abase + brow[1];
    bf16x8 af0[4], bf0[4], af1[4], bf1[4];
    af0[0] = ldsr128<0>(a0);    af0[1] = ldsr128<2048>(a0);
    af0[2] = ldsr128<4096>(a0); af0[3] = ldsr128<6144>(a0);
    bf0[0] = ldsr128<0>(b0);    bf0[1] = ldsr128<2048>(b0);
    bf0[2] = ldsr128<4096>(b0); bf0[3] = ldsr128<6144>(b0);
    af1[0] = ldsr128<0>(a1);    af1[1] = ldsr128<2048>(a1);
    af1[2] = ldsr128<4096>(a1); af1[3] = ldsr128<6144>(a1);
    bf1[0] = ldsr128<0>(b1);    bf1[1] = ldsr128<2048>(b1);
    bf1[2] = ldsr128<4096>(b1); bf1[3] = ldsr128<6144>(b1);
    SCHEDB;
    WAIT_LGKM8;
    SCHEDB;
    __builtin_amdgcn_s_setprio(1);
#pragma unroll
    for (int mt = 0; mt < 4; ++mt)
#pragma unroll
      for (int nt = 0; nt < 4; ++nt)
        acc[mt][nt] = __builtin_amdgcn_mfma_f32_16x16x32_bf16(
            af0[mt], bf0[nt], acc[mt][nt], 0, 0, 0);
    __builtin_amdgcn_s_setprio(0);
    WAIT_LGKM0;
    SCHEDB;
    __builtin_amdgcn_s_setprio(1);
#pragma unroll
    for (int mt = 0; mt < 4; ++mt)
#pragma unroll
      for (int nt = 0; nt < 4; ++nt)
        acc[mt][nt] = __builtin_amdgcn_mfma_f32_16x16x32_bf16(
            af1[mt], bf1[nt], acc[mt][nt], 0, 0, 0);
    __builtin_amdgcn_s_setprio(0);
  }

  if (MODE == 0) {
#pragma unroll
    for (int mt = 0; mt < 4; ++mt)
#pragma unroll
      for (int r = 0; r < 4; ++r) {
        int grow = row0 + wr + mt * 16 + quad * 4 + r;
#pragma unroll
        for (int nt = 0; nt < 4; ++nt)
          C[(size_t)grow * N + col0 + wc + nt * 16 + lm] = acc[mt][nt][r];
      }
  } else {
    const int seg = col0 >> 10;                   // 0=q, 1=k, 2=v (uniform/block)
    if (seg < 2) {
      u16* dst = seg ? kws : qws;
      const float qs = seg ? 1.0f : 0.125f;       // D^-0.5 on q
      const int colb = (col0 & 1023) + wc;
#pragma unroll
      for (int mt = 0; mt < 4; ++mt)
#pragma unroll
        for (int r = 0; r < 4; ++r) {
          int sg = row0 + wr + mt * 16 + quad * 4 + r;
          int b = sg >> 11, s = sg & 2047;
#pragma unroll
          for (int nt = 0; nt < 4; ++nt) {
            int nn = colb + nt * 16 + lm;
            int h = nn >> 6, d = nn & 63;
            float val = acc[mt][nt][r] * qs;
            float2 cs = rtab[(s << 5) + (d >> 1)];
            float partner = __shfl_xor(val, 1);
            float o = (d & 1) ? fmaf(val, cs.x, partner * cs.y)
                              : fmaf(val, cs.x, -partner * cs.y);
            dst[((size_t)((b * NH + h) * SLEN + s)) * 64 + d] = f2b(o);
          }
        }
    } else {
      // v: blend with residual by mix, transpose to (b,h,d,s) via LDS.
      const int h0 = (col0 - 2048) >> 6;
      const int p = w & 1;
      const int b = row0 >> 11, s0 = row0 & 2047;
      const int bh = b * NH + h0 + p;
      u16* VtW = smem + p * 8704;                 // per-head 64*136 u16
      __syncthreads();                            // main-loop smem retired
#pragma unroll
      for (int mt = 0; mt < 4; ++mt)
#pragma unroll
        for (int nt = 0; nt < 4; ++nt) {
          const int d = nt * 16 + lm;
          const int sl = wr + mt * 16 + quad * 4;
          union { u16 u[4]; u64 ll; } pk;
#pragma unroll
          for (int r = 0; r < 4; ++r) {
            int s = s0 + sl + r;
            float val = acc[mt][nt][r];
            float mv = mixws[bh * SLEN + s];
            float o = val + (vres[((size_t)(bh * SLEN + s)) * 64 + d] - val) * mv;
            pk.u[r] = f2b(o);
          }
          *reinterpret_cast<u64*>(&VtW[d * 136 + sl]) = pk.ll;
        }
      __syncthreads();
#pragma unroll
      for (int it = 0; it < 8; ++it) {
        int idx = it * 256 + tid;
        int ph = idx >> 10, rem = idx & 1023;
        int d = rem >> 4, ch = rem & 15;
        const u16* src = smem + ph * 8704 + d * 136 + ch * 8;
        u16* dstp = vws + ((size_t)((b * NH + h0 + ph) * 64 + d)) * SLEN + s0 + ch * 8;
        *reinterpret_cast<uint4*>(dstp) = *reinterpret_cast<const uint4*>(src);
      }
    }
  }
}

// ---------------- MFMA flash attention: QBLK=128, 8 waves, swizzled K/V dbuf ----
// 1024 blocks x 512 thr; each block covers 128 q-rows of one head, so the
// ~9-tile K/V window is loaded ONCE per 128 rows (was per 64: traffic halved,
// barrier chains 18 -> ~10). LDS 50.4KB + 512 thr -> up to 24 waves/CU (2x).
// Per-wave activity skip: wave w (rows wlo..wlo+15) computes tile c only if
// [c0, c0+63] intersects [wlo-WIN, whi]; barriers stay outside the branch.
// XCD pinning (T1): bh = ((sid>>7)<<3)|(sid&7) -> one XCD owns a head's K/V.
__global__ __launch_bounds__(512) void attn_mfma_kernel(
    const u16* __restrict__ q, const u16* __restrict__ k, const u16* __restrict__ vt,
    const float* __restrict__ gate, u16* __restrict__ X) {
  __shared__ __align__(16) u16 Ks[2][4096];   // [buf][j 64][8 swizzled 16B chunks]
  __shared__ __align__(16) u16 Vs[2][4096];   // [buf][d 64][8 swizzled 16B chunks]
  __shared__ __align__(16) u16 Ps[8][16][72]; // [wave][q-local][j 64 + pad]
  const int tid = threadIdx.x;
  const int w = tid >> 6, lane = tid & 63;
  const int lm = lane & 15, quad = lane >> 4;
  const int sid = blockIdx.x;                 // 1024 = 8 grp x 16 qt x 8 r
  const int qt = (sid >> 3) & 15;
  const int bh = ((sid >> 7) << 3) | (sid & 7);
  const int h = bh & 15;
  const int b = bh >> 4;
  const int q0 = qt * 128;
  const size_t kqbase = (size_t)bh * SLEN * 64;   // q,k: (b,h,s,d)
  const size_t vbase  = (size_t)bh * 64 * SLEN;   // vt: (b,h,d,s)

  bf16x8 qf[2];
  {
    const u16* qrow = q + kqbase + (size_t)(q0 + w * 16 + lm) * 64;
    qf[0] = *reinterpret_cast<const bf16x8*>(qrow + quad * 8);
    qf[1] = *reinterpret_cast<const bf16x8*>(qrow + 32 + quad * 8);
  }

  floatx4 o[4];
#pragma unroll
  for (int nt = 0; nt < 4; ++nt) o[nt] = (floatx4){0.f, 0.f, 0.f, 0.f};
  float lsum = 0.f;
  const int iq = q0 + w * 16 + lm;
  const int wlo = q0 + w * 16, whi = wlo + 15;

  const int c_first = (q0 >= WIN) ? ((q0 - WIN) >> 6) : 0;
  const int c_last = (q0 + 127) >> 6;

  const int sr = tid >> 3;                            // staging row 0..63
  const int scz = ((tid & 7) ^ (sr & 7)) * 8;         // inverse-swizzled chunk
  const u32 ksbase = (u32)(size_t)(__attribute__((address_space(3))) u16*)&Ks[0][0];
  const u32 vsbase = (u32)(size_t)(__attribute__((address_space(3))) u16*)&Vs[0][0];
  const u32 psbase = (u32)(size_t)(__attribute__((address_space(3))) u16*)&Ps[0][0][0];
  const int rxa8 = lm & 7;
  const u32 rowoff = (u32)lm * 128 + (u32)((quad ^ rxa8) * 16);
  const u32 paddr = psbase + (u32)(w * 16 + lm) * 144 + (u32)quad * 16;

  auto stage = [&](int c, int buf) {                  // full 8KB K + 8KB V tile
    const u16* kg = k + kqbase + (size_t)(c << 6) * 64;
    const u16* vg = vt + vbase + (c << 6);
    gl2lds16(kg + sr * 64 + scz, &Ks[buf][0] + tid * 8);
    gl2lds16(vg + (size_t)sr * SLEN + scz, &Vs[buf][0] + tid * 8);
  };

  stage(c_first, 0);
  int cur = 0;
  for (int c = c_first; c <= c_last; ++c) {
    const int c0 = c << 6;
    // __syncthreads drains vmcnt: buf[cur] landed block-wide; prev reads of
    // buf[cur^1] ordered before the prefetch below overwrites it.
    __syncthreads();
    if (c < c_last) stage(c + 1, cur ^ 1);

    // per-wave skip: does [c0, c0+63] intersect [wlo-WIN, whi]?
    const bool wactive = (c0 <= whi) && (c0 + 63 + WIN >= wlo);
    if (wactive) {
      // ---- QK^T: K frags via swizzled asm ds_read (conflict-free) ----
      const u32 kof = ksbase + (u32)(cur << 13) + rowoff;
      const u32 kof4 = kof ^ 64u;
      bf16x8 k00 = ldsr128<0>(kof),     k01 = ldsr128<2048>(kof),
             k02 = ldsr128<4096>(kof),  k03 = ldsr128<6144>(kof);
      bf16x8 k10 = ldsr128<0>(kof4),    k11 = ldsr128<2048>(kof4),
             k12 = ldsr128<4096>(kof4), k13 = ldsr128<6144>(kof4);
      SCHEDB;
      WAIT_LGKM0;
      SCHEDB;
      floatx4 st[4];
      const floatx4 z4 = (floatx4){0.f, 0.f, 0.f, 0.f};
      __builtin_amdgcn_s_setprio(1);
      st[0] = __builtin_amdgcn_mfma_f32_16x16x32_bf16(k00, qf[0], z4, 0, 0, 0);
      st[0] = __builtin_amdgcn_mfma_f32_16x16x32_bf16(k10, qf[1], st[0], 0, 0, 0);
      st[1] = __builtin_amdgcn_mfma_f32_16x16x32_bf16(k01, qf[0], z4, 0, 0, 0);
      st[1] = __builtin_amdgcn_mfma_f32_16x16x32_bf16(k11, qf[1], st[1], 0, 0, 0);
      st[2] = __builtin_amdgcn_mfma_f32_16x16x32_bf16(k02, qf[0], z4, 0, 0, 0);
      st[2] = __builtin_amdgcn_mfma_f32_16x16x32_bf16(k12, qf[1], st[2], 0, 0, 0);
      st[3] = __builtin_amdgcn_mfma_f32_16x16x32_bf16(k03, qf[0], z4, 0, 0, 0);
      st[3] = __builtin_amdgcn_mfma_f32_16x16x32_bf16(k13, qf[1], st[3], 0, 0, 0);
      __builtin_amdgcn_s_setprio(0);

      const bool need_mask = (c0 + 63 > wlo) || (c0 < whi - WIN);
      if (need_mask) {
#pragma unroll
        for (int mt = 0; mt < 4; ++mt)
#pragma unroll
          for (int r = 0; r < 4; ++r) {
            int j = c0 + mt * 16 + quad * 4 + r;
            bool valid = (j <= iq) && (j >= iq - WIN);
            if (!valid) st[mt][r] = -3.0e38f;
          }
      }
      float p[4][4], psum = 0.f;
#pragma unroll
      for (int mt = 0; mt < 4; ++mt)
#pragma unroll
        for (int r = 0; r < 4; ++r) {
          p[mt][r] = __expf(st[mt][r]);
          psum += p[mt][r];
        }
      psum += __shfl_xor(psum, 16);
      psum += __shfl_xor(psum, 32);
      lsum += psum;
#pragma unroll
      for (int mt = 0; mt < 4; ++mt) {
        union { u16 u[4]; u64 ll; } pk;
#pragma unroll
        for (int r = 0; r < 4; ++r) pk.u[r] = f2b(p[mt][r]);
        *reinterpret_cast<u64*>(&Ps[w][lm][mt * 16 + quad * 4]) = pk.ll;
      }
      __builtin_amdgcn_wave_barrier();
      __builtin_amdgcn_s_waitcnt(0xC07F);   // lgkmcnt(0): Ps writes visible
      __builtin_amdgcn_wave_barrier();

      // ---- PV: P frags + V frags via asm ds_read (swizzled, conflict-free) ----
      bf16x8 pa0 = ldsr128<0>(paddr), pa1 = ldsr128<64>(paddr);
      const u32 vof = vsbase + (u32)(cur << 13) + rowoff;
      const u32 vof4 = vof ^ 64u;
      bf16x8 v00 = ldsr128<0>(vof),     v01 = ldsr128<2048>(vof),
             v02 = ldsr128<4096>(vof),  v03 = ldsr128<6144>(vof);
      bf16x8 v10 = ldsr128<0>(vof4),    v11 = ldsr128<2048>(vof4),
             v12 = ldsr128<4096>(vof4), v13 = ldsr128<6144>(vof4);
      SCHEDB;
      WAIT_LGKM0;
      SCHEDB;
      __builtin_amdgcn_s_setprio(1);
      o[0] = __builtin_amdgcn_mfma_f32_16x16x32_bf16(pa0, v00, o[0], 0, 0, 0);
      o[0] = __builtin_amdgcn_mfma_f32_16x16x32_bf16(pa1, v10, o[0], 0, 0, 0);
      o[1] = __builtin_amdgcn_mfma_f32_16x16x32_bf16(pa0, v01, o[1], 0, 0, 0);
      o[1] = __builtin_amdgcn_mfma_f32_16x16x32_bf16(pa1, v11, o[1], 0, 0, 0);
      o[2] = __builtin_amdgcn_mfma_f32_16x16x32_bf16(pa0, v02, o[2], 0, 0, 0);
      o[2] = __builtin_amdgcn_mfma_f32_16x16x32_bf16(pa1, v12, o[2], 0, 0, 0);
      o[3] = __builtin_amdgcn_mfma_f32_16x16x32_bf16(pa0, v03, o[3], 0, 0, 0);
      o[3] = __builtin_amdgcn_mfma_f32_16x16x32_bf16(pa1, v13, o[3], 0, 0, 0);
      __builtin_amdgcn_s_setprio(0);
    }

    cur ^= 1;
  }
  float linv[4], g[4];
#pragma unroll
  for (int r = 0; r < 4; ++r) {
    linv[r] = 1.0f / __shfl(lsum, quad * 4 + r);
    g[r] = gate[bh * SLEN + q0 + w * 16 + quad * 4 + r];
  }
#pragma unroll
  for (int r = 0; r < 4; ++r) {
    int i = q0 + w * 16 + quad * 4 + r;
    u16* xrow = X + ((size_t)(b * SLEN + i)) * 1024 + h * 64;
#pragma unroll
    for (int nt = 0; nt < 4; ++nt)
      xrow[nt * 16 + lm] = f2b(o[nt][r] * linv[r] * g[r]);
  }
}

// ---------------- launch ----------------
extern "C" void kernel_launch(void* const* d_in, const int* in_sizes, int n_in,
                              void* d_out, int out_size, void* d_ws, size_t ws_size,
                              hipStream_t stream) {
  (void)in_sizes; (void)n_in; (void)out_size; (void)ws_size;
  const float* tokens = (const float*)d_in[0];
  const float* vres   = (const float*)d_in[1];
  const float* Wq     = (const float*)d_in[2];
  const float* Wkv    = (const float*)d_in[3];
  const float* Wout   = (const float*)d_in[4];
  const float* Wgate  = (const float*)d_in[5];
  const float* Wmix   = (const float*)d_in[6];
  float* out = (float*)d_out;

  char* p = (char*)d_ws;
  auto alloc = [&](size_t bytes) { char* r = p; p += (bytes + 255) & ~(size_t)255; return r; };
  u16*  tokA   = (u16*)alloc(8192ull * 1024 * 2);
  u16*  WqkvT  = (u16*)alloc(3072ull * 1024 * 2);
  u16*  WoutT  = (u16*)alloc(1024ull * 1024 * 2);
  u16*  Wmg    = (u16*)alloc(32ull * 1024 * 2);
  float2* rtab = (float2*)alloc(65536ull * 8);
  u16*  qws    = (u16*)alloc(8388608ull * 2);       // (b,h,s,d) post rotary+scale
  u16*  kws    = (u16*)alloc(8388608ull * 2);       // (b,h,s,d) post rotary
  u16*  vws    = (u16*)alloc(8388608ull * 2);       // (b,h,d,s) transposed, post mix
  u16*  Xws    = (u16*)alloc(8388608ull * 2);       // attn out (b,s,h*d), post gate
  float* mixws = (float*)alloc(131072ull * 4);
  float* gatews= (float*)alloc(131072ull * 4);

  prep_all<<<9600, 256, 0, stream>>>(tokens, Wq, Wkv, Wout, Wmix, Wgate,
      (u64*)tokA, WqkvT, WoutT, Wmg, rtab);
  mixgate_mfma<<<256, 128, 0, stream>>>(tokA, Wmg, mixws, gatews);
  gemm_pipe<1><<<1536, 256, 0, stream>>>(tokA, WqkvT, nullptr,
      qws, kws, vws, vres, mixws, rtab, 3072);
  attn_mfma_kernel<<<1024, 512, 0, stream>>>(qws, kws, vws, gatews, Xws);
  gemm_pipe<0><<<512, 256, 0, stream>>>(Xws, WoutT, out,
      nullptr, nullptr, nullptr, nullptr, nullptr, nullptr, 1024);
}